// Round 6
// baseline (270.385 us; speedup 1.0000x reference)
//
#include <hip/hip_runtime.h>
#include <stdint.h>

// Problem: B=2, S=2048, D=1024, H=16, dh=64
// Inputs fp32, OUTPUT fp32. Internals bf16 (threshold has bf16 floor).
#define SEQ    2048
#define DMODEL 1024

typedef __bf16 bf16x8 __attribute__((ext_vector_type(8)));
typedef float  f32x4  __attribute__((ext_vector_type(4)));

typedef __attribute__((address_space(1))) const void CGV;  // global
typedef __attribute__((address_space(3))) void LDSV;       // LDS

__device__ __forceinline__ void load_lds16(const void* g, void* l) {
    __builtin_amdgcn_global_load_lds((CGV*)g, (LDSV*)l, 16, 0, 0);
}

// native v_exp_f32 (llvm.exp2.f32 is legal on amdgcn)
__device__ __forceinline__ float fast_exp2(float x) { return __builtin_exp2f(x); }

// ---------------------------------------------------------------------------
// Transpose+convert: in f32 [R][C] -> out bf16 [C][R].  grid (C/32, R/32), 256 thr
// ---------------------------------------------------------------------------
__global__ __launch_bounds__(256)
void transpose_f32_to_bf16(const float* __restrict__ in, __bf16* __restrict__ out,
                           int R, int C)
{
    __shared__ float tile[32][33];
    const int t  = threadIdx.x;
    const int tx = t & 31, ty = t >> 5;          // ty 0..7
    const int c0 = blockIdx.x * 32;
    const int r0 = blockIdx.y * 32;
#pragma unroll
    for (int i = 0; i < 4; ++i)
        tile[ty + i * 8][tx] = in[(size_t)(r0 + ty + i * 8) * C + c0 + tx];
    __syncthreads();
#pragma unroll
    for (int i = 0; i < 4; ++i)
        out[(size_t)(c0 + ty + i * 8) * R + r0 + tx] = (__bf16)tile[tx][ty + i * 8];
}

// ---------------------------------------------------------------------------
// f32 -> bf16 convert (vectorized). grid n/(256*8), 256 thr
// ---------------------------------------------------------------------------
__global__ __launch_bounds__(256)
void convert_f32_to_bf16(const float* __restrict__ in, __bf16* __restrict__ out)
{
    const int i = (blockIdx.x * 256 + threadIdx.x) * 8;
    float4 a = *(const float4*)(in + i);
    float4 b = *(const float4*)(in + i + 4);
    __bf16 tmp[8] = { (__bf16)a.x, (__bf16)a.y, (__bf16)a.z, (__bf16)a.w,
                      (__bf16)b.x, (__bf16)b.y, (__bf16)b.z, (__bf16)b.w };
    *(uint4*)(out + i) = *(uint4*)tmp;
}

// ---------------------------------------------------------------------------
// V transpose (bf16): in [32][2048][64] -> out [32][64][2048]
// grid (SEQ/32, 64/32, 32), 256 thr
// ---------------------------------------------------------------------------
__global__ __launch_bounds__(256)
void transpose_v(const __bf16* __restrict__ in, __bf16* __restrict__ out)
{
    __shared__ __bf16 tile[32][34];
    const int t  = threadIdx.x;
    const int tx = t & 31, ty = t >> 5;
    const int s0 = blockIdx.x * 32;
    const int d0 = blockIdx.y * 32;
    const int bh = blockIdx.z;
    const __bf16* ip = in  + (size_t)bh * SEQ * 64;
    __bf16*       op = out + (size_t)bh * 64 * SEQ;
#pragma unroll
    for (int i = 0; i < 4; ++i)
        tile[ty + i * 8][tx] = ip[(size_t)(s0 + ty + i * 8) * 64 + d0 + tx];
    __syncthreads();
#pragma unroll
    for (int i = 0; i < 4; ++i)
        op[(size_t)(d0 + ty + i * 8) * SEQ + s0 + tx] = tile[tx][ty + i * 8];
}

// ---------------------------------------------------------------------------
// GEMM (m97 structure): C[M x N] = A[M x K] @ Bt[N x K]^T + bias[N]
// ---------------------------------------------------------------------------
template<bool A_IS_F32>
__global__ __launch_bounds__(256)
void gemm_kernel(const void* __restrict__ Av, const __bf16* __restrict__ Bt,
                 const float* __restrict__ bias,
                 __bf16* __restrict__ Cq, __bf16* __restrict__ Ck,
                 __bf16* __restrict__ Cv, float* __restrict__ Cplain,
                 int K, int N, int mode)
{
    __shared__ __attribute__((aligned(16))) __bf16 As[128][32];
    __shared__ __attribute__((aligned(16))) __bf16 Bs[128][32];

    const int t    = threadIdx.x;
    const int wave = __builtin_amdgcn_readfirstlane(t >> 6);
    const int lane = t & 63;
    const int l15  = lane & 15;
    const int quad = lane >> 4;
    const int wm   = (wave >> 1) * 64;
    const int wn   = (wave & 1) * 64;
    const int m0   = blockIdx.y * 128;
    const int n0   = blockIdx.x * 128;

    const int arow  = lane >> 2;        // 0..15 within a 16-row slab
    const int akoff = (lane & 3) * 8;   // lane covers 8 bf16 of k

    f32x4 acc[4][4] = {};

    for (int k0 = 0; k0 < K; k0 += 32) {
        __syncthreads();
        // ---- stage A 128x32 ----
        if (A_IS_F32) {
            const float* A = (const float*)Av;
            int row = t >> 1, kk = (t & 1) * 16;
            const float* srcp = A + (size_t)(m0 + row) * K + k0 + kk;
            float4 v0 = *(const float4*)(srcp);
            float4 v1 = *(const float4*)(srcp + 4);
            float4 v2 = *(const float4*)(srcp + 8);
            float4 v3 = *(const float4*)(srcp + 12);
            __bf16 tmp[16] = {
                (__bf16)v0.x, (__bf16)v0.y, (__bf16)v0.z, (__bf16)v0.w,
                (__bf16)v1.x, (__bf16)v1.y, (__bf16)v1.z, (__bf16)v1.w,
                (__bf16)v2.x, (__bf16)v2.y, (__bf16)v2.z, (__bf16)v2.w,
                (__bf16)v3.x, (__bf16)v3.y, (__bf16)v3.z, (__bf16)v3.w };
            *(uint4*)(&As[row][kk])     = *(uint4*)(tmp);
            *(uint4*)(&As[row][kk + 8]) = *(uint4*)(tmp + 8);
        } else {
            const __bf16* A = (const __bf16*)Av;
#pragma unroll
            for (int p = 0; p < 2; ++p) {
                int slab = (wave * 2 + p) * 16;
                const __bf16* g = A + (size_t)(m0 + slab + arow) * K + k0 + akoff;
                load_lds16(g, &As[slab][0]);   // HW: base + lane*16
            }
        }
        // ---- stage B 128x32 via global_load_lds (Bt is [N][K] bf16) ----
#pragma unroll
        for (int p = 0; p < 2; ++p) {
            int slab = (wave * 2 + p) * 16;
            const __bf16* g = Bt + (size_t)(n0 + slab + arow) * K + k0 + akoff;
            load_lds16(g, &Bs[slab][0]);
        }
        __syncthreads();   // drains vmcnt (global_load_lds) + lgkm

        bf16x8 af[4], bfr[4];
#pragma unroll
        for (int mi = 0; mi < 4; ++mi)
            af[mi] = *(const bf16x8*)(&As[wm + mi * 16 + l15][quad * 8]);
#pragma unroll
        for (int ni = 0; ni < 4; ++ni)
            bfr[ni] = *(const bf16x8*)(&Bs[wn + ni * 16 + l15][quad * 8]);
#pragma unroll
        for (int mi = 0; mi < 4; ++mi)
#pragma unroll
            for (int ni = 0; ni < 4; ++ni)
                acc[mi][ni] = __builtin_amdgcn_mfma_f32_16x16x32_bf16(
                    af[mi], bfr[ni], acc[mi][ni], 0, 0, 0);
    }

    // epilogue: C/D layout col=lane&15, row=quad*4+reg
#pragma unroll
    for (int mi = 0; mi < 4; ++mi) {
        int rowb = m0 + wm + mi * 16 + quad * 4;
#pragma unroll
        for (int ni = 0; ni < 4; ++ni) {
            int col = n0 + wn + ni * 16 + l15;
            float bia = bias[col];
#pragma unroll
            for (int r = 0; r < 4; ++r) {
                float v = acc[mi][ni][r] + bia;
                int rr = rowb + r;
                if (mode == 0) {
                    int b = rr >> 11;
                    int s = rr & 2047;
                    int part = col >> 10;
                    int rem  = col & 1023;
                    int h = rem >> 6;
                    int d = rem & 63;
                    __bf16* dst = (part == 0) ? Cq : (part == 1) ? Ck : Cv;
                    dst[(((size_t)(b * 16 + h)) * SEQ + s) * 64 + d] = (__bf16)v;
                } else {
                    Cplain[(size_t)rr * N + col] = v;   // fp32 output
                }
            }
        }
    }
}

// ---------------------------------------------------------------------------
// MFMA flash attention v6 = v5 pipeline + 32 q rows per wave (2 groups) +
// exp2-domain softmax + defer-rescale (T13, THR=8 log2).
//   - v5-verified: K/V LDS dbuf via global_load_lds staged 1 tile ahead,
//     ONE s_barrier + vmcnt(0) per tile, both-sides XOR swizzle, S^T softmax,
//     wave-local Ps sync, loop-carried register mask buffer.
//   - NEW: each wave owns 32 q (groups g=0,1 at q0+g*16+l15). K/V ds_reads
//     shared by both groups (8 reads -> 32 MFMAs). Two independent softmax
//     chains per wave. Per-tile fixed costs amortized 2x.
//   - NEW: scores kept in log2 domain (C1=0.125*log2e, C2=1e4*log2e);
//     P = exp2(s2 - m2). Defer-rescale: skip alpha/broadcast/rescale unless
//     some row's max grew > 8 (wave-uniform __any branch).
//   - LDS = 16K Kt + 16K Vt + 16K Ps = 49152 B. grid (32, 16), 2 blocks/CU.
// ---------------------------------------------------------------------------
__global__ __launch_bounds__(256, 2)
void attn_kernel(const __bf16* __restrict__ Q, const __bf16* __restrict__ Kb,
                 const __bf16* __restrict__ Vtg, const float* __restrict__ mask,
                 __bf16* __restrict__ Out)
{
    __shared__ __attribute__((aligned(16))) __bf16 Kt[2][64 * 64]; // [key][d] swz
    __shared__ __attribute__((aligned(16))) __bf16 Vt[2][64 * 64]; // [d][key] swz
    __shared__ __attribute__((aligned(16))) __bf16 Ps[4][32 * 64]; // [q][key] swz

    const int t    = threadIdx.x;
    const int wave = __builtin_amdgcn_readfirstlane(t >> 6);
    const int lane = t & 63;
    const int l15  = lane & 15;
    const int quad = lane >> 4;
    const int swq  = lane & 7;                  // == l15 & 7
    const int bh   = blockIdx.x;
    const int b    = bh >> 4;
    const int h    = bh & 15;
    const int q0   = blockIdx.y * 128 + wave * 32;

    const float C1 = 0.180336880f;    // 0.125 * log2(e)
    const float C2 = 14426.9502f;     // 1e4  * log2(e)

    const __bf16* Qp  = Q   + (size_t)bh * SEQ * 64;
    const __bf16* Kp  = Kb  + (size_t)bh * SEQ * 64;
    const __bf16* Vtp = Vtg + (size_t)bh * 64 * SEQ;   // [d][s]
    const float*  Mrow0 = mask + (size_t)b * SEQ * SEQ + (size_t)(q0 + l15) * SEQ + quad * 4;
    const float*  Mrow1 = Mrow0 + (size_t)16 * SEQ;

    // ---- stage-source lane constants (v5-verified swizzle family) ----
    const int ch  = wave * 2;
    const int rw0 = ch * 8 + (lane >> 3);
    const int swz = ((lane & 7) ^ (lane >> 3)) * 8;
    const __bf16* kS0 = Kp  + (size_t)rw0 * 64 + swz;
    const __bf16* kS1 = Kp  + (size_t)(rw0 + 8) * 64 + swz;
    const __bf16* vS0 = Vtp + (size_t)rw0 * SEQ + swz;
    const __bf16* vS1 = Vtp + (size_t)(rw0 + 8) * SEQ + swz;

    bf16x8 qf00, qf01, qf10, qf11;
    qf00 = *(const bf16x8*)(Qp + (size_t)(q0 + l15) * 64 + quad * 8);
    qf01 = *(const bf16x8*)(Qp + (size_t)(q0 + l15) * 64 + 32 + quad * 8);
    qf10 = *(const bf16x8*)(Qp + (size_t)(q0 + 16 + l15) * 64 + quad * 8);
    qf11 = *(const bf16x8*)(Qp + (size_t)(q0 + 16 + l15) * 64 + 32 + quad * 8);

    f32x4 oacc0[4] = {}, oacc1[4] = {};
    float mrun0 = -1e30f, lrun0 = 0.f;
    float mrun1 = -1e30f, lrun1 = 0.f;

    // ---- prologue: stage tile 0 into buf0, mask tile 0 into regs ----
    load_lds16(kS0, &Kt[0][ch * 512]);
    load_lds16(kS1, &Kt[0][(ch + 1) * 512]);
    load_lds16(vS0, &Vt[0][ch * 512]);
    load_lds16(vS1, &Vt[0][(ch + 1) * 512]);
    f32x4 mk0[4], mk1[4];
#pragma unroll
    for (int nb = 0; nb < 4; ++nb) {
        mk0[nb] = *(const f32x4*)(Mrow0 + nb * 16);
        mk1[nb] = *(const f32x4*)(Mrow1 + nb * 16);
    }

    const char* PsW0 = (const char*)&Ps[wave][0] + l15 * 128;
    const char* PsW1 = PsW0 + 16 * 128;

#pragma unroll 2
    for (int tt = 0; tt < SEQ / 64; ++tt) {
        const int key0 = tt * 64;
        const int keyn = (key0 + 64 <= SEQ - 64) ? key0 + 64 : SEQ - 64;
        const int cur  = tt & 1;
        const char* kcur = (const char*)&Kt[cur][0];
        const char* vcur = (const char*)&Vt[cur][0];
        __bf16* knxt = &Kt[cur ^ 1][0];
        __bf16* vnxt = &Vt[cur ^ 1][0];

        // --- top-of-tile: loads staged last tile done; publish buffers ---
        asm volatile("s_waitcnt vmcnt(0)" ::: "memory");
        __builtin_amdgcn_s_barrier();
        __builtin_amdgcn_sched_barrier(0);

        // --- issue stage of tile t+1 (async; drained at NEXT tile top) ---
        load_lds16(kS0 + (size_t)keyn * 64, knxt + ch * 512);
        load_lds16(kS1 + (size_t)keyn * 64, knxt + (ch + 1) * 512);
        load_lds16(vS0 + keyn, vnxt + ch * 512);
        load_lds16(vS1 + keyn, vnxt + (ch + 1) * 512);
        __builtin_amdgcn_sched_barrier(0);

        // --- QK for both q-groups; kf shared (8 ds_reads -> 16 MFMAs) ---
        f32x4 sa0[4], sa1[4];
#pragma unroll
        for (int nb = 0; nb < 4; ++nb) {
            const char* kb = kcur + (nb * 16 + l15) * 128;
            bf16x8 kf0 = *(const bf16x8*)(kb + (((quad) ^ swq) << 4));
            bf16x8 kf1 = *(const bf16x8*)(kb + (((4 + quad) ^ swq) << 4));
            f32x4 z0 = {}, z1 = {};
            z0 = __builtin_amdgcn_mfma_f32_16x16x32_bf16(kf0, qf00, z0, 0, 0, 0);
            z1 = __builtin_amdgcn_mfma_f32_16x16x32_bf16(kf0, qf10, z1, 0, 0, 0);
            z0 = __builtin_amdgcn_mfma_f32_16x16x32_bf16(kf1, qf01, z0, 0, 0, 0);
            z1 = __builtin_amdgcn_mfma_f32_16x16x32_bf16(kf1, qf11, z1, 0, 0, 0);
            sa0[nb] = z0;
            sa1[nb] = z1;
        }

        // --- mask + scale in log2 domain (consume mk), prefetch mask(t+1) ---
#pragma unroll
        for (int nb = 0; nb < 4; ++nb)
#pragma unroll
            for (int r = 0; r < 4; ++r) {
                float t0 = __fmaf_rn(C1, sa0[nb][r], C2);
                float t1 = __fmaf_rn(C1, sa1[nb][r], C2);
                sa0[nb][r] = __fmaf_rn(mk0[nb][r], t0, -C2);
                sa1[nb][r] = __fmaf_rn(mk1[nb][r], t1, -C2);
            }
#pragma unroll
        for (int nb = 0; nb < 4; ++nb) {
            mk0[nb] = *(const f32x4*)(Mrow0 + keyn + nb * 16);
            mk1[nb] = *(const f32x4*)(Mrow1 + keyn + nb * 16);
        }

        // --- per-group row max (q=l15 lane-local 16 keys, 2 shfl) ---
        float v0 = fmaxf(fmaxf(sa0[0][0], sa0[0][1]), fmaxf(sa0[0][2], sa0[0][3]));
        float v1 = fmaxf(fmaxf(sa1[0][0], sa1[0][1]), fmaxf(sa1[0][2], sa1[0][3]));
#pragma unroll
        for (int nb = 1; nb < 4; ++nb) {
            v0 = fmaxf(v0, fmaxf(fmaxf(sa0[nb][0], sa0[nb][1]), fmaxf(sa0[nb][2], sa0[nb][3])));
            v1 = fmaxf(v1, fmaxf(fmaxf(sa1[nb][0], sa1[nb][1]), fmaxf(sa1[nb][2], sa1[nb][3])));
        }
        v0 = fmaxf(v0, __shfl_xor(v0, 16));
        v1 = fmaxf(v1, __shfl_xor(v1, 16));
        v0 = fmaxf(v0, __shfl_xor(v0, 32));
        v1 = fmaxf(v1, __shfl_xor(v1, 32));

        // --- defer-rescale (T13): only rescale when max grew > 8 (log2) ---
        float al0 = 1.f, al1 = 1.f;
        bool need = (v0 > mrun0 + 8.f) || (v1 > mrun1 + 8.f);
        if (__any(need)) {
            float nm0 = fmaxf(mrun0, v0);
            float nm1 = fmaxf(mrun1, v1);
            al0 = fast_exp2(mrun0 - nm0);
            al1 = fast_exp2(mrun1 - nm1);
            mrun0 = nm0;
            mrun1 = nm1;
            float a0[4], a1[4];
#pragma unroll
            for (int r = 0; r < 4; ++r) {
                a0[r] = __shfl(al0, quad * 4 + r);
                a1[r] = __shfl(al1, quad * 4 + r);
            }
#pragma unroll
            for (int cb = 0; cb < 4; ++cb)
#pragma unroll
                for (int r = 0; r < 4; ++r) {
                    oacc0[cb][r] *= a0[r];
                    oacc1[cb][r] *= a1[r];
                }
        }

        // --- P = exp2(s2 - m2); row sums ---
        float ac0 = 0.f, ac1 = 0.f;
#pragma unroll
        for (int nb = 0; nb < 4; ++nb)
#pragma unroll
            for (int r = 0; r < 4; ++r) {
                float p0 = fast_exp2(sa0[nb][r] - mrun0);
                float p1 = fast_exp2(sa1[nb][r] - mrun1);
                sa0[nb][r] = p0;
                sa1[nb][r] = p1;
                ac0 += p0;
                ac1 += p1;
            }
        ac0 += __shfl_xor(ac0, 16);
        ac1 += __shfl_xor(ac1, 16);
        ac0 += __shfl_xor(ac0, 32);
        ac1 += __shfl_xor(ac1, 32);
        lrun0 = lrun0 * al0 + ac0;
        lrun1 = lrun1 * al1 + ac1;

        // --- pack P -> Ps (swizzled, wave-private): 8 x 8B stores ---
#pragma unroll
        for (int nb = 0; nb < 4; ++nb) {
            union { __bf16 hh[4]; uint2 u; } p0, p1;
            p0.hh[0] = (__bf16)sa0[nb][0];
            p0.hh[1] = (__bf16)sa0[nb][1];
            p0.hh[2] = (__bf16)sa0[nb][2];
            p0.hh[3] = (__bf16)sa0[nb][3];
            p1.hh[0] = (__bf16)sa1[nb][0];
            p1.hh[1] = (__bf16)sa1[nb][1];
            p1.hh[2] = (__bf16)sa1[nb][2];
            p1.hh[3] = (__bf16)sa1[nb][3];
            const int so = (((nb * 2 + (quad >> 1)) ^ swq) << 4) + (quad & 1) * 8;
            *(uint2*)(PsW0 + so) = p0.u;
            *(uint2*)(PsW1 + so) = p1.u;
        }
        asm volatile("s_waitcnt lgkmcnt(0)" ::: "memory");
        __builtin_amdgcn_sched_barrier(0);

        bf16x8 pf00 = *(const bf16x8*)(PsW0 + (((quad) ^ swq) << 4));
        bf16x8 pf01 = *(const bf16x8*)(PsW0 + (((4 + quad) ^ swq) << 4));
        bf16x8 pf10 = *(const bf16x8*)(PsW1 + (((quad) ^ swq) << 4));
        bf16x8 pf11 = *(const bf16x8*)(PsW1 + (((4 + quad) ^ swq) << 4));

        // --- O += P V; vf shared by both groups ---
        __builtin_amdgcn_s_setprio(1);
#pragma unroll
        for (int cb = 0; cb < 4; ++cb) {
            const char* vb = vcur + (cb * 16 + l15) * 128;
            bf16x8 vf0 = *(const bf16x8*)(vb + (((quad) ^ swq) << 4));
            bf16x8 vf1 = *(const bf16x8*)(vb + (((4 + quad) ^ swq) << 4));
            oacc0[cb] = __builtin_amdgcn_mfma_f32_16x16x32_bf16(pf00, vf0, oacc0[cb], 0, 0, 0);
            oacc1[cb] = __builtin_amdgcn_mfma_f32_16x16x32_bf16(pf10, vf0, oacc1[cb], 0, 0, 0);
            oacc0[cb] = __builtin_amdgcn_mfma_f32_16x16x32_bf16(pf01, vf1, oacc0[cb], 0, 0, 0);
            oacc1[cb] = __builtin_amdgcn_mfma_f32_16x16x32_bf16(pf11, vf1, oacc1[cb], 0, 0, 0);
        }
        __builtin_amdgcn_s_setprio(0);
    }

    // epilogue: l broadcast per group, bf16 Ao out
    float l40[4], l41[4];
#pragma unroll
    for (int r = 0; r < 4; ++r) {
        l40[r] = __shfl(lrun0, quad * 4 + r);
        l41[r] = __shfl(lrun1, quad * 4 + r);
    }
#pragma unroll
    for (int cb = 0; cb < 4; ++cb) {
#pragma unroll
        for (int r = 0; r < 4; ++r) {
            int qq0 = q0 + quad * 4 + r;
            Out[((size_t)(b * SEQ + qq0)) * DMODEL + h * 64 + cb * 16 + l15] =
                (__bf16)(oacc0[cb][r] / l40[r]);
            Out[((size_t)(b * SEQ + qq0 + 16)) * DMODEL + h * 64 + cb * 16 + l15] =
                (__bf16)(oacc1[cb][r] / l41[r]);
        }
    }
}

// ---------------------------------------------------------------------------
extern "C" void kernel_launch(void* const* d_in, const int* in_sizes, int n_in,
                              void* d_out, int out_size, void* d_ws, size_t ws_size,
                              hipStream_t stream)
{
    const float* src  = nullptr;  // 4194304
    const float* mask = nullptr;  // 8388608
    const float* Wqkv = nullptr;  // 3145728
    const float* bqkv = nullptr;  // 3072
    const float* Wout = nullptr;  // 1048576
    const float* bout = nullptr;  // 1024
    for (int i = 0; i < n_in; ++i) {
        switch (in_sizes[i]) {
            case 4194304: src  = (const float*)d_in[i]; break;
            case 8388608: mask = (const float*)d_in[i]; break;
            case 3145728: Wqkv = (const float*)d_in[i]; break;
            case 3072:    bqkv = (const float*)d_in[i]; break;
            case 1048576: Wout = (const float*)d_in[i]; break;
            case 1024:    bout = (const float*)d_in[i]; break;
        }
    }
    float* out = (float*)d_out;                  // [2,2048,1024] fp32

    const size_t NE = (size_t)2 * 16 * SEQ * 64; // 4M elems
    __bf16* Qb     = (__bf16*)d_ws;              // 4M
    __bf16* Kb     = Qb + NE;                    // 4M
    __bf16* Vb     = Kb + NE;                    // 4M (dead after transpose_v)
    __bf16* Vtg    = Vb + NE;                    // 4M
    __bf16* Wqkv_t = Vtg + NE;                   // 3M  [3072][1024]
    __bf16* Wout_t = Wqkv_t + (size_t)3072 * 1024; // 1M [1024][1024]
    __bf16* Ao     = Vb;                         // alias: Vb dead by then
    __bf16* SrcBf  = Vtg;                        // alias: Vtg written only later
    // total: 4+4+4+4+3+1 = 20M bf16 = 40MB

    // weight transposes (bf16 convert)
    transpose_f32_to_bf16<<<dim3(3072 / 32, 1024 / 32), 256, 0, stream>>>(
        Wqkv, Wqkv_t, 1024, 3072);
    transpose_f32_to_bf16<<<dim3(1024 / 32, 1024 / 32), 256, 0, stream>>>(
        Wout, Wout_t, 1024, 1024);

    // src -> bf16 (enables gll A-path in GEMM1); lives in Vtg until transpose_v
    convert_f32_to_bf16<<<dim3(4194304 / (256 * 8)), 256, 0, stream>>>(src, SrcBf);

    // GEMM1: src_bf16 @ Wqkv -> scatter Q/K/V
    gemm_kernel<false><<<dim3(3072 / 128, 4096 / 128), 256, 0, stream>>>(
        (const void*)SrcBf, Wqkv_t, bqkv, Qb, Kb, Vb, nullptr, 1024, 3072, 0);

    // V -> V^T (overwrites SrcBf alias; SrcBf dead after GEMM1)
    transpose_v<<<dim3(SEQ / 32, 2, 32), 256, 0, stream>>>(Vb, Vtg);

    // attention
    attn_kernel<<<dim3(32, SEQ / 128), 256, 0, stream>>>(Qb, Kb, Vtg, mask, Ao);

    // GEMM2: Ao(bf16) @ Wout + b -> out (fp32)
    gemm_kernel<false><<<dim3(1024 / 128, 4096 / 128), 256, 0, stream>>>(
        (const void*)Ao, Wout_t, bout, nullptr, nullptr, nullptr, out, 1024, 1024, 1);
}

// Round 7
// 265.132 us; speedup vs baseline: 1.0198x; 1.0198x over previous
//
#include <hip/hip_runtime.h>
#include <stdint.h>

// Problem: B=2, S=2048, D=1024, H=16, dh=64
// Inputs fp32, OUTPUT fp32. Internals bf16 (threshold has bf16 floor).
#define SEQ    2048
#define DMODEL 1024

typedef __bf16 bf16x8 __attribute__((ext_vector_type(8)));
typedef float  f32x4  __attribute__((ext_vector_type(4)));

typedef __attribute__((address_space(1))) const void CGV;  // global
typedef __attribute__((address_space(3))) void LDSV;       // LDS

__device__ __forceinline__ void load_lds16(const void* g, void* l) {
    __builtin_amdgcn_global_load_lds((CGV*)g, (LDSV*)l, 16, 0, 0);
}

// native v_exp_f32 (llvm.exp2.f32 is legal on amdgcn)
__device__ __forceinline__ float fast_exp2(float x) { return __builtin_exp2f(x); }

// ---------------------------------------------------------------------------
// Transpose+convert: in f32 [R][C] -> out bf16 [C][R].  grid (C/32, R/32), 256 thr
// ---------------------------------------------------------------------------
__global__ __launch_bounds__(256)
void transpose_f32_to_bf16(const float* __restrict__ in, __bf16* __restrict__ out,
                           int R, int C)
{
    __shared__ float tile[32][33];
    const int t  = threadIdx.x;
    const int tx = t & 31, ty = t >> 5;          // ty 0..7
    const int c0 = blockIdx.x * 32;
    const int r0 = blockIdx.y * 32;
#pragma unroll
    for (int i = 0; i < 4; ++i)
        tile[ty + i * 8][tx] = in[(size_t)(r0 + ty + i * 8) * C + c0 + tx];
    __syncthreads();
#pragma unroll
    for (int i = 0; i < 4; ++i)
        out[(size_t)(c0 + ty + i * 8) * R + r0 + tx] = (__bf16)tile[tx][ty + i * 8];
}

// ---------------------------------------------------------------------------
// f32 -> bf16 convert (vectorized). grid n/(256*8), 256 thr
// ---------------------------------------------------------------------------
__global__ __launch_bounds__(256)
void convert_f32_to_bf16(const float* __restrict__ in, __bf16* __restrict__ out)
{
    const int i = (blockIdx.x * 256 + threadIdx.x) * 8;
    float4 a = *(const float4*)(in + i);
    float4 b = *(const float4*)(in + i + 4);
    __bf16 tmp[8] = { (__bf16)a.x, (__bf16)a.y, (__bf16)a.z, (__bf16)a.w,
                      (__bf16)b.x, (__bf16)b.y, (__bf16)b.z, (__bf16)b.w };
    *(uint4*)(out + i) = *(uint4*)tmp;
}

// ---------------------------------------------------------------------------
// V transpose (bf16): in [32][2048][64] -> out [32][64][2048]
// grid (SEQ/32, 64/32, 32), 256 thr
// ---------------------------------------------------------------------------
__global__ __launch_bounds__(256)
void transpose_v(const __bf16* __restrict__ in, __bf16* __restrict__ out)
{
    __shared__ __bf16 tile[32][34];
    const int t  = threadIdx.x;
    const int tx = t & 31, ty = t >> 5;
    const int s0 = blockIdx.x * 32;
    const int d0 = blockIdx.y * 32;
    const int bh = blockIdx.z;
    const __bf16* ip = in  + (size_t)bh * SEQ * 64;
    __bf16*       op = out + (size_t)bh * 64 * SEQ;
#pragma unroll
    for (int i = 0; i < 4; ++i)
        tile[ty + i * 8][tx] = ip[(size_t)(s0 + ty + i * 8) * 64 + d0 + tx];
    __syncthreads();
#pragma unroll
    for (int i = 0; i < 4; ++i)
        op[(size_t)(d0 + ty + i * 8) * SEQ + s0 + tx] = tile[tx][ty + i * 8];
}

// ---------------------------------------------------------------------------
// GEMM v7: m97 fragment structure + 2-phase double-buffered pipeline (T3-min).
//   stage(t+1) issued BEFORE compute(t); ONE vmcnt(0)+s_barrier per K-step
//   (drains the stage issued last step, covered by last step's compute).
//   A is always bf16 [M][K]; Bt is bf16 [N][K].  LDS = 2x(8K+8K) = 32KB.
// mode 0: scatter bf16 into Q/K/V [B,H,S,dh];  mode 1: fp32 row-major store.
// ---------------------------------------------------------------------------
__global__ __launch_bounds__(256)
void gemm_kernel(const __bf16* __restrict__ A, const __bf16* __restrict__ Bt,
                 const float* __restrict__ bias,
                 __bf16* __restrict__ Cq, __bf16* __restrict__ Ck,
                 __bf16* __restrict__ Cv, float* __restrict__ Cplain,
                 int K, int N, int mode)
{
    __shared__ __attribute__((aligned(16))) __bf16 As[2][128][32];
    __shared__ __attribute__((aligned(16))) __bf16 Bs[2][128][32];

    const int t    = threadIdx.x;
    const int wave = __builtin_amdgcn_readfirstlane(t >> 6);
    const int lane = t & 63;
    const int l15  = lane & 15;
    const int quad = lane >> 4;
    const int wm   = (wave >> 1) * 64;
    const int wn   = (wave & 1) * 64;
    const int m0   = blockIdx.y * 128;
    const int n0   = blockIdx.x * 128;

    const int arow  = lane >> 2;        // 0..15 within a 16-row slab
    const int akoff = (lane & 3) * 8;   // lane covers 8 bf16 of k

    f32x4 acc[4][4] = {};

#define GSTAGE(buf, kk)                                                        \
    {                                                                          \
        _Pragma("unroll")                                                      \
        for (int p = 0; p < 2; ++p) {                                          \
            int slab = (wave * 2 + p) * 16;                                    \
            load_lds16(A  + (size_t)(m0 + slab + arow) * K + (kk) + akoff,     \
                       &As[buf][slab][0]);                                     \
            load_lds16(Bt + (size_t)(n0 + slab + arow) * K + (kk) + akoff,     \
                       &Bs[buf][slab][0]);                                     \
        }                                                                      \
    }

    GSTAGE(0, 0);
    int cur = 0;
#pragma unroll 2
    for (int k0 = 0; k0 < K; k0 += 32) {
        // drain the stage issued last step (covered by last step's compute)
        asm volatile("s_waitcnt vmcnt(0)" ::: "memory");
        __builtin_amdgcn_s_barrier();
        __builtin_amdgcn_sched_barrier(0);
        if (k0 + 32 < K) GSTAGE(cur ^ 1, k0 + 32);
        __builtin_amdgcn_sched_barrier(0);

        bf16x8 af[4], bfr[4];
#pragma unroll
        for (int mi = 0; mi < 4; ++mi)
            af[mi] = *(const bf16x8*)(&As[cur][wm + mi * 16 + l15][quad * 8]);
#pragma unroll
        for (int ni = 0; ni < 4; ++ni)
            bfr[ni] = *(const bf16x8*)(&Bs[cur][wn + ni * 16 + l15][quad * 8]);
#pragma unroll
        for (int mi = 0; mi < 4; ++mi)
#pragma unroll
            for (int ni = 0; ni < 4; ++ni)
                acc[mi][ni] = __builtin_amdgcn_mfma_f32_16x16x32_bf16(
                    af[mi], bfr[ni], acc[mi][ni], 0, 0, 0);
        cur ^= 1;
    }
#undef GSTAGE

    // epilogue: C/D layout col=lane&15, row=quad*4+reg
#pragma unroll
    for (int mi = 0; mi < 4; ++mi) {
        int rowb = m0 + wm + mi * 16 + quad * 4;
#pragma unroll
        for (int ni = 0; ni < 4; ++ni) {
            int col = n0 + wn + ni * 16 + l15;
            float bia = bias[col];
#pragma unroll
            for (int r = 0; r < 4; ++r) {
                float v = acc[mi][ni][r] + bia;
                int rr = rowb + r;
                if (mode == 0) {
                    int b = rr >> 11;
                    int s = rr & 2047;
                    int part = col >> 10;
                    int rem  = col & 1023;
                    int h = rem >> 6;
                    int d = rem & 63;
                    __bf16* dst = (part == 0) ? Cq : (part == 1) ? Ck : Cv;
                    dst[(((size_t)(b * 16 + h)) * SEQ + s) * 64 + d] = (__bf16)v;
                } else {
                    Cplain[(size_t)rr * N + col] = v;   // fp32 output
                }
            }
        }
    }
}

// ---------------------------------------------------------------------------
// MFMA flash attention v7 = v6 math (2 q-groups/wave, exp2 softmax,
// defer-rescale) with finer sync domains + counted waits:
//   - 2-wave blocks of 64 q -> grid (32,32)=1024 blocks, 4 blocks/CU
//     (LDS 40960 = 16K Kt + 16K Vt + 8K Ps). Same 8 waves/CU as v6 but
//     4 independent blocks and 2-wave barriers.
//   - T4 counted wait: tile-top s_waitcnt vmcnt(8) drains exactly the 8
//     gll staging loads (oldest) and leaves the 8 mask prefetch loads
//     (younger, HBM) outstanding until their compiler-inserted use-wait.
//     v6's vmcnt(0) serialized on HBM mask latency every tile.
//   - ONE barrier per tile; wave-local Ps sync (lgkmcnt) as before.
// ---------------------------------------------------------------------------
__global__ __launch_bounds__(128, 2)
void attn_kernel(const __bf16* __restrict__ Q, const __bf16* __restrict__ Kb,
                 const __bf16* __restrict__ Vtg, const float* __restrict__ mask,
                 __bf16* __restrict__ Out)
{
    __shared__ __attribute__((aligned(16))) __bf16 Kt[2][64 * 64]; // [key][d] swz
    __shared__ __attribute__((aligned(16))) __bf16 Vt[2][64 * 64]; // [d][key] swz
    __shared__ __attribute__((aligned(16))) __bf16 Ps[2][32 * 64]; // [q][key] swz

    const int t    = threadIdx.x;
    const int wave = __builtin_amdgcn_readfirstlane(t >> 6);   // 0..1
    const int lane = t & 63;
    const int l15  = lane & 15;
    const int quad = lane >> 4;
    const int swq  = lane & 7;                  // == l15 & 7
    const int bh   = blockIdx.x;
    const int b    = bh >> 4;
    const int h    = bh & 15;
    const int q0   = blockIdx.y * 64 + wave * 32;

    const float C1 = 0.180336880f;    // 0.125 * log2(e)
    const float C2 = 14426.9502f;     // 1e4  * log2(e)

    const __bf16* Qp  = Q   + (size_t)bh * SEQ * 64;
    const __bf16* Kp  = Kb  + (size_t)bh * SEQ * 64;
    const __bf16* Vtp = Vtg + (size_t)bh * 64 * SEQ;   // [d][s]
    const float*  Mrow0 = mask + (size_t)b * SEQ * SEQ + (size_t)(q0 + l15) * SEQ + quad * 4;
    const float*  Mrow1 = Mrow0 + (size_t)16 * SEQ;

    // ---- stage-source lane constants (v5-verified swizzle family) ----
    // 8 chunks of 8 rows; wave covers chunks wave*4 .. wave*4+3.
    // lane L in chunk c: row c*8+(L>>3), LDS slot (L&7), src slot (L&7)^(L>>3).
    const int swz = ((lane & 7) ^ (lane >> 3)) * 8;
    const __bf16* kS[4];
    const __bf16* vS[4];
#pragma unroll
    for (int p = 0; p < 4; ++p) {
        int rw = wave * 32 + p * 8 + (lane >> 3);
        kS[p] = Kp  + (size_t)rw * 64 + swz;
        vS[p] = Vtp + (size_t)rw * SEQ + swz;
    }

    // Q fragments first in the vmcnt FIFO (drained by first top-wait)
    bf16x8 qf00, qf01, qf10, qf11;
    qf00 = *(const bf16x8*)(Qp + (size_t)(q0 + l15) * 64 + quad * 8);
    qf01 = *(const bf16x8*)(Qp + (size_t)(q0 + l15) * 64 + 32 + quad * 8);
    qf10 = *(const bf16x8*)(Qp + (size_t)(q0 + 16 + l15) * 64 + quad * 8);
    qf11 = *(const bf16x8*)(Qp + (size_t)(q0 + 16 + l15) * 64 + 32 + quad * 8);

    f32x4 oacc0[4] = {}, oacc1[4] = {};
    float mrun0 = -1e30f, lrun0 = 0.f;
    float mrun1 = -1e30f, lrun1 = 0.f;

#define STAGE_KV(bufidx, key)                                                 \
    {                                                                         \
        _Pragma("unroll")                                                     \
        for (int p = 0; p < 4; ++p) {                                         \
            load_lds16(kS[p] + (size_t)(key) * 64,                            \
                       &Kt[bufidx][(wave * 4 + p) * 512]);                    \
            load_lds16(vS[p] + (key), &Vt[bufidx][(wave * 4 + p) * 512]);     \
        }                                                                     \
    }

    // ---- prologue: stage tile 0 (8 gll), THEN mask tile 0 (8 vmem) ----
    STAGE_KV(0, 0);
    f32x4 mk0[4], mk1[4];
#pragma unroll
    for (int nb = 0; nb < 4; ++nb) {
        mk0[nb] = *(const f32x4*)(Mrow0 + nb * 16);
        mk1[nb] = *(const f32x4*)(Mrow1 + nb * 16);
    }

    const char* PsW0 = (const char*)&Ps[wave][0] + l15 * 128;
    const char* PsW1 = PsW0 + 16 * 128;

#pragma unroll 2
    for (int tt = 0; tt < SEQ / 64; ++tt) {
        const int key0 = tt * 64;
        const int keyn = (key0 + 64 <= SEQ - 64) ? key0 + 64 : SEQ - 64;
        const int cur  = tt & 1;
        const char* kcur = (const char*)&Kt[cur][0];
        const char* vcur = (const char*)&Vt[cur][0];

        // --- tile top: drain EXACTLY the 8 staging glls (oldest); the 8
        //     mask prefetch loads (younger) stay outstanding (T4). ---
        asm volatile("s_waitcnt vmcnt(8)" ::: "memory");
        __builtin_amdgcn_s_barrier();
        __builtin_amdgcn_sched_barrier(0);

        // --- issue stage of tile t+1 (async; drained at NEXT tile top) ---
        if (tt < SEQ / 64 - 1) STAGE_KV(cur ^ 1, key0 + 64);
        __builtin_amdgcn_sched_barrier(0);

        // --- QK for both q-groups; kf shared (8 ds_reads -> 16 MFMAs) ---
        f32x4 sa0[4], sa1[4];
#pragma unroll
        for (int nb = 0; nb < 4; ++nb) {
            const char* kb = kcur + (nb * 16 + l15) * 128;
            bf16x8 kf0 = *(const bf16x8*)(kb + (((quad) ^ swq) << 4));
            bf16x8 kf1 = *(const bf16x8*)(kb + (((4 + quad) ^ swq) << 4));
            f32x4 z0 = {}, z1 = {};
            z0 = __builtin_amdgcn_mfma_f32_16x16x32_bf16(kf0, qf00, z0, 0, 0, 0);
            z1 = __builtin_amdgcn_mfma_f32_16x16x32_bf16(kf0, qf10, z1, 0, 0, 0);
            z0 = __builtin_amdgcn_mfma_f32_16x16x32_bf16(kf1, qf01, z0, 0, 0, 0);
            z1 = __builtin_amdgcn_mfma_f32_16x16x32_bf16(kf1, qf11, z1, 0, 0, 0);
            sa0[nb] = z0;
            sa1[nb] = z1;
        }

        // --- mask + scale in log2 domain (consume mk), prefetch mask(t+1) ---
#pragma unroll
        for (int nb = 0; nb < 4; ++nb)
#pragma unroll
            for (int r = 0; r < 4; ++r) {
                float t0 = __fmaf_rn(C1, sa0[nb][r], C2);
                float t1 = __fmaf_rn(C1, sa1[nb][r], C2);
                sa0[nb][r] = __fmaf_rn(mk0[nb][r], t0, -C2);
                sa1[nb][r] = __fmaf_rn(mk1[nb][r], t1, -C2);
            }
#pragma unroll
        for (int nb = 0; nb < 4; ++nb) {
            mk0[nb] = *(const f32x4*)(Mrow0 + keyn + nb * 16);
            mk1[nb] = *(const f32x4*)(Mrow1 + keyn + nb * 16);
        }

        // --- per-group row max (q=l15 lane-local 16 keys, 2 shfl) ---
        float v0 = fmaxf(fmaxf(sa0[0][0], sa0[0][1]), fmaxf(sa0[0][2], sa0[0][3]));
        float v1 = fmaxf(fmaxf(sa1[0][0], sa1[0][1]), fmaxf(sa1[0][2], sa1[0][3]));
#pragma unroll
        for (int nb = 1; nb < 4; ++nb) {
            v0 = fmaxf(v0, fmaxf(fmaxf(sa0[nb][0], sa0[nb][1]), fmaxf(sa0[nb][2], sa0[nb][3])));
            v1 = fmaxf(v1, fmaxf(fmaxf(sa1[nb][0], sa1[nb][1]), fmaxf(sa1[nb][2], sa1[nb][3])));
        }
        v0 = fmaxf(v0, __shfl_xor(v0, 16));
        v1 = fmaxf(v1, __shfl_xor(v1, 16));
        v0 = fmaxf(v0, __shfl_xor(v0, 32));
        v1 = fmaxf(v1, __shfl_xor(v1, 32));

        // --- defer-rescale (T13): only rescale when max grew > 8 (log2) ---
        float al0 = 1.f, al1 = 1.f;
        bool need = (v0 > mrun0 + 8.f) || (v1 > mrun1 + 8.f);
        if (__any(need)) {
            float nm0 = fmaxf(mrun0, v0);
            float nm1 = fmaxf(mrun1, v1);
            al0 = fast_exp2(mrun0 - nm0);
            al1 = fast_exp2(mrun1 - nm1);
            mrun0 = nm0;
            mrun1 = nm1;
            float a0[4], a1[4];
#pragma unroll
            for (int r = 0; r < 4; ++r) {
                a0[r] = __shfl(al0, quad * 4 + r);
                a1[r] = __shfl(al1, quad * 4 + r);
            }
#pragma unroll
            for (int cb = 0; cb < 4; ++cb)
#pragma unroll
                for (int r = 0; r < 4; ++r) {
                    oacc0[cb][r] *= a0[r];
                    oacc1[cb][r] *= a1[r];
                }
        }

        // --- P = exp2(s2 - m2); row sums ---
        float ac0 = 0.f, ac1 = 0.f;
#pragma unroll
        for (int nb = 0; nb < 4; ++nb)
#pragma unroll
            for (int r = 0; r < 4; ++r) {
                float p0 = fast_exp2(sa0[nb][r] - mrun0);
                float p1 = fast_exp2(sa1[nb][r] - mrun1);
                sa0[nb][r] = p0;
                sa1[nb][r] = p1;
                ac0 += p0;
                ac1 += p1;
            }
        ac0 += __shfl_xor(ac0, 16);
        ac1 += __shfl_xor(ac1, 16);
        ac0 += __shfl_xor(ac0, 32);
        ac1 += __shfl_xor(ac1, 32);
        lrun0 = lrun0 * al0 + ac0;
        lrun1 = lrun1 * al1 + ac1;

        // --- pack P -> Ps (swizzled, wave-private): 8 x 8B stores ---
#pragma unroll
        for (int nb = 0; nb < 4; ++nb) {
            union { __bf16 hh[4]; uint2 u; } p0, p1;
            p0.hh[0] = (__bf16)sa0[nb][0];
            p0.hh[1] = (__bf16)sa0[nb][1];
            p0.hh[2] = (__bf16)sa0[nb][2];
            p0.hh[3] = (__bf16)sa0[nb][3];
            p1.hh[0] = (__bf16)sa1[nb][0];
            p1.hh[1] = (__bf16)sa1[nb][1];
            p1.hh[2] = (__bf16)sa1[nb][2];
            p1.hh[3] = (__bf16)sa1[nb][3];
            const int so = (((nb * 2 + (quad >> 1)) ^ swq) << 4) + (quad & 1) * 8;
            *(uint2*)(PsW0 + so) = p0.u;
            *(uint2*)(PsW1 + so) = p1.u;
        }
        asm volatile("s_waitcnt lgkmcnt(0)" ::: "memory");
        __builtin_amdgcn_sched_barrier(0);

        bf16x8 pf00 = *(const bf16x8*)(PsW0 + (((quad) ^ swq) << 4));
        bf16x8 pf01 = *(const bf16x8*)(PsW0 + (((4 + quad) ^ swq) << 4));
        bf16x8 pf10 = *(const bf16x8*)(PsW1 + (((quad) ^ swq) << 4));
        bf16x8 pf11 = *(const bf16x8*)(PsW1 + (((4 + quad) ^ swq) << 4));

        // --- O += P V; vf shared by both groups ---
        __builtin_amdgcn_s_setprio(1);
#pragma unroll
        for (int cb = 0; cb < 4; ++cb) {
            const char* vb = vcur + (cb * 16 + l15) * 128;
            bf16x8 vf0 = *(const bf16x8*)(vb + (((quad) ^ swq) << 4));
            bf16x8 vf1 = *(const bf16x8*)(vb + (((4 + quad) ^ swq) << 4));
            oacc0[cb] = __builtin_amdgcn_mfma_f32_16x16x32_bf16(pf00, vf0, oacc0[cb], 0, 0, 0);
            oacc1[cb] = __builtin_amdgcn_mfma_f32_16x16x32_bf16(pf10, vf0, oacc1[cb], 0, 0, 0);
            oacc0[cb] = __builtin_amdgcn_mfma_f32_16x16x32_bf16(pf01, vf1, oacc0[cb], 0, 0, 0);
            oacc1[cb] = __builtin_amdgcn_mfma_f32_16x16x32_bf16(pf11, vf1, oacc1[cb], 0, 0, 0);
        }
        __builtin_amdgcn_s_setprio(0);
    }
#undef STAGE_KV

    // epilogue: l broadcast per group, bf16 Ao out
    float l40[4], l41[4];
#pragma unroll
    for (int r = 0; r < 4; ++r) {
        l40[r] = __shfl(lrun0, quad * 4 + r);
        l41[r] = __shfl(lrun1, quad * 4 + r);
    }
#pragma unroll
    for (int cb = 0; cb < 4; ++cb) {
#pragma unroll
        for (int r = 0; r < 4; ++r) {
            int qq0 = q0 + quad * 4 + r;
            Out[((size_t)(b * SEQ + qq0)) * DMODEL + h * 64 + cb * 16 + l15] =
                (__bf16)(oacc0[cb][r] / l40[r]);
            Out[((size_t)(b * SEQ + qq0 + 16)) * DMODEL + h * 64 + cb * 16 + l15] =
                (__bf16)(oacc1[cb][r] / l41[r]);
        }
    }
}

// ---------------------------------------------------------------------------
extern "C" void kernel_launch(void* const* d_in, const int* in_sizes, int n_in,
                              void* d_out, int out_size, void* d_ws, size_t ws_size,
                              hipStream_t stream)
{
    const float* src  = nullptr;  // 4194304
    const float* mask = nullptr;  // 8388608
    const float* Wqkv = nullptr;  // 3145728
    const float* bqkv = nullptr;  // 3072
    const float* Wout = nullptr;  // 1048576
    const float* bout = nullptr;  // 1024
    for (int i = 0; i < n_in; ++i) {
        switch (in_sizes[i]) {
            case 4194304: src  = (const float*)d_in[i]; break;
            case 8388608: mask = (const float*)d_in[i]; break;
            case 3145728: Wqkv = (const float*)d_in[i]; break;
            case 3072:    bqkv = (const float*)d_in[i]; break;
            case 1048576: Wout = (const float*)d_in[i]; break;
            case 1024:    bout = (const float*)d_in[i]; break;
        }
    }
    float* out = (float*)d_out;                  // [2,2048,1024] fp32

    const size_t NE = (size_t)2 * 16 * SEQ * 64; // 4M elems
    __bf16* Qb     = (__bf16*)d_ws;              // 4M
    __bf16* Kb     = Qb + NE;                    // 4M
    __bf16* Vb     = Kb + NE;                    // 4M (dead after transpose_v)
    __bf16* Vtg    = Vb + NE;                    // 4M
    __bf16* Wqkv_t = Vtg + NE;                   // 3M  [3072][1024]
    __bf16* Wout_t = Wqkv_t + (size_t)3072 * 1024; // 1M [1024][1024]
    __bf16* Ao     = Vb;                         // alias: Vb dead by then
    __bf16* SrcBf  = Vtg;                        // alias: Vtg written only later
    // total: 4+4+4+4+3+1 = 20M bf16 = 40MB

    // weight transposes (bf16 convert)
    transpose_f32_to_bf16<<<dim3(3072 / 32, 1024 / 32), 256, 0, stream>>>(
        Wqkv, Wqkv_t, 1024, 3072);
    transpose_f32_to_bf16<<<dim3(1024 / 32, 1024 / 32), 256, 0, stream>>>(
        Wout, Wout_t, 1024, 1024);

    // src -> bf16 (enables gll A-path in GEMM1); lives in Vtg until transpose_v
    convert_f32_to_bf16<<<dim3(4194304 / (256 * 8)), 256, 0, stream>>>(src, SrcBf);

    // GEMM1: src_bf16 @ Wqkv -> scatter Q/K/V
    gemm_kernel<<<dim3(3072 / 128, 4096 / 128), 256, 0, stream>>>(
        SrcBf, Wqkv_t, bqkv, Qb, Kb, Vb, nullptr, 1024, 3072, 0);

    // V -> V^T (overwrites SrcBf alias; SrcBf dead after GEMM1)
    transpose_v<<<dim3(SEQ / 32, 2, 32), 256, 0, stream>>>(Vb, Vtg);

    // attention: 1024 blocks of 128 threads (2 waves, 64 q each)
    attn_kernel<<<dim3(32, SEQ / 64), 128, 0, stream>>>(Qb, Kb, Vtg, mask, Ao);

    // GEMM2: Ao(bf16) @ Wout + b -> out (fp32)
    gemm_kernel<<<dim3(1024 / 128, 4096 / 128), 256, 0, stream>>>(
        Ao, Wout_t, bout, nullptr, nullptr, nullptr, out, 1024, 1024, 1);
}